// Round 4
// baseline (412.472 us; speedup 1.0000x reference)
//
#include <hip/hip_runtime.h>
#include <cmath>

typedef __attribute__((ext_vector_type(8))) short short8;
typedef __attribute__((ext_vector_type(4))) float f32x4;
typedef __attribute__((ext_vector_type(4))) unsigned short us4;
typedef unsigned short u16;

#define BATCH 8192
#define HDIM  256
static constexpr size_t BH = (size_t)BATCH * HDIM;  // 2,097,152

__device__ __forceinline__ u16 f2bf(float f) {
    union { float f; unsigned u; } v; v.f = f;
    unsigned r = v.u + 0x7FFFu + ((v.u >> 16) & 1u);
    return (u16)(r >> 16);
}
__device__ __forceinline__ float bf2f(u16 u) {
    union { unsigned u; float f; } v; v.u = ((unsigned)u) << 16;
    return v.f;
}
__device__ __forceinline__ float wred(float v) {
#pragma unroll
    for (int o = 32; o > 0; o >>= 1) v += __shfl_xor(v, o);
    return v;
}
__device__ __forceinline__ float sigmoidf_(float x) {
    return 1.f / (1.f + __expf(-x));
}
__device__ __forceinline__ short8 cvt8(const float* p) {
    f32x4 lo = *(const f32x4*)p, hi = *(const f32x4*)(p + 4);
    short8 t;
    t[0] = (short)f2bf(lo[0]); t[1] = (short)f2bf(lo[1]);
    t[2] = (short)f2bf(lo[2]); t[3] = (short)f2bf(lo[3]);
    t[4] = (short)f2bf(hi[0]); t[5] = (short)f2bf(hi[1]);
    t[6] = (short)f2bf(hi[2]); t[7] = (short)f2bf(hi[3]);
    return t;
}

// ---------------- weight conversion: pack all needed weights to bf16 ----------------
// dst layout (u16 units, 65536 per chunk):
//  c0: embed_w | c1..4: wtn[l] | c5..8: wsn[l] | c9..12: wt[l][512:768]
//  c13..16: ws[l][0:256] | c17..20: ws[l][512:768] | c21: out_w
__global__ __launch_bounds__(256) void convert_weights(
    const float* __restrict__ embed_w, const float* __restrict__ wtn,
    const float* __restrict__ wsn, const float* __restrict__ wt,
    const float* __restrict__ ws, const float* __restrict__ out_w,
    u16* __restrict__ dst)
{
    int idx = blockIdx.x * 256 + threadIdx.x;
    int e = idx * 4;
    if (e >= 22 * 65536) return;
    int c = e >> 16, o = e & 65535;
    const float* src;
    if (c == 0)      src = embed_w + o;
    else if (c < 5)  src = wtn + (size_t)(c - 1) * 65536 + o;
    else if (c < 9)  src = wsn + (size_t)(c - 5) * 65536 + o;
    else if (c < 13) src = wt + (size_t)(c - 9) * 768 * 256 + 512 * 256 + o;
    else if (c < 17) src = ws + (size_t)(c - 13) * 768 * 256 + o;
    else if (c < 21) src = ws + (size_t)(c - 17) * 768 * 256 + 512 * 256 + o;
    else             src = out_w + o;
    f32x4 v = *(const f32x4*)src;
    us4 r;
#pragma unroll
    for (int j = 0; j < 4; ++j) r[j] = f2bf(v[j]);
    *(us4*)(dst + e) = r;
}

// ---------------- mega kernel v2: 1024 thr (16 waves), 16 rows/block ----------------
// GEMM phases: wave w owns output columns [16w, 16w+16).
// Attention phase: wave w owns batch row w (one wave per row, no serial rows).
#define PAD 264  // u16 row stride (528 B: 16B-aligned, breaks power-of-2 bank pattern)
__global__ __launch_bounds__(1024, 8) void stau_mega(
    const float* __restrict__ x,
    const float* __restrict__ t_att, const float* __restrict__ s_att,
    const u16* __restrict__ Wbf,
    const float* __restrict__ embed_b,
    const float* __restrict__ btn, const float* __restrict__ bsn,
    const float* __restrict__ bt, const float* __restrict__ bs,
    const float* __restrict__ out_b,
    float* __restrict__ outp)
{
    __shared__ __align__(16) u16 S_lds[5][16][PAD];  // S history (bf16)
    __shared__ __align__(16) u16 sn_lds[16][PAD];    // s_next (bf16)
    __shared__ __align__(16) u16 tn_lds[16][PAD];    // t_next (bf16)
    __shared__ __align__(16) u16 tf_lds[16][PAD];    // T_fusion (bf16)
    __shared__ __align__(16) u16 sf_lds[16][PAD];    // S_fusion (bf16)

    const int lane = threadIdx.x & 63;
    const int wave = threadIdx.x >> 6;  // 0..15
    const int lr = lane & 15;
    const int kg = lane >> 4;
    const int row0 = blockIdx.x * 16;
    const int n0 = wave * 16;           // GEMM column block
    const float scale = 0.0625f;        // 1/sqrt(256)

    // ---- embed: S0 = x @ embed_w^T + embed_b ----
    {
        f32x4 acc = {};
        for (int k0 = 0; k0 < 256; k0 += 32) {
            int k = k0 + kg * 8;
            short8 a = cvt8(x + (size_t)(row0 + lr) * 256 + k);
            short8 b = *(const short8*)(Wbf + (size_t)(n0 + lr) * 256 + k);
            acc = __builtin_amdgcn_mfma_f32_16x16x32_bf16(a, b, acc, 0, 0, 0);
        }
        float bn = embed_b[n0 + lr];
#pragma unroll
        for (int r = 0; r < 4; ++r)
            S_lds[0][kg * 4 + r][n0 + lr] = f2bf(acc[r] + bn);
    }
    __syncthreads();

    for (int i = 0; i < 4; ++i) {
        // ---- phase 1: s_next and t_next, 16 cols per wave each ----
        {
            const u16* Wsn = Wbf + (size_t)(5 + i) * 65536;
            const u16* Wtn = Wbf + (size_t)(1 + i) * 65536;
            f32x4 accS = {}, accT = {};
            for (int k0 = 0; k0 < 256; k0 += 32) {
                int k = k0 + kg * 8;
                short8 aS = *(const short8*)(&S_lds[i][lr][k]);
                short8 aT = cvt8(t_att + ((size_t)i * 8 + 7) * BH + (size_t)(row0 + lr) * 256 + k);
                size_t wo = (size_t)(n0 + lr) * 256 + k;
                accS = __builtin_amdgcn_mfma_f32_16x16x32_bf16(aS, *(const short8*)(Wsn + wo), accS, 0, 0, 0);
                accT = __builtin_amdgcn_mfma_f32_16x16x32_bf16(aT, *(const short8*)(Wtn + wo), accT, 0, 0, 0);
            }
            float bS = bsn[i * 256 + n0 + lr];
            float bT = btn[i * 256 + n0 + lr];
#pragma unroll
            for (int r = 0; r < 4; ++r) {
                sn_lds[kg * 4 + r][n0 + lr] = f2bf(accS[r] + bS);
                tn_lds[kg * 4 + r][n0 + lr] = f2bf(accT[r] + bT);
            }
        }
        __syncthreads();

        // ---- phase 2: attention + gating (wave w -> row w) ----
        {
            const int rr = wave;
            const size_t ro = (size_t)(row0 + rr) * 256 + lane * 4;
            us4 snu = *(const us4*)&sn_lds[rr][lane * 4];
            us4 tnu = *(const us4*)&tn_lds[rr][lane * 4];
            us4 scu = *(const us4*)&S_lds[i][rr][lane * 4];
            float sn[4], tn[4], Sc[4];
#pragma unroll
            for (int j = 0; j < 4; ++j) { sn[j] = bf2f(snu[j]); tn[j] = bf2f(tnu[j]); Sc[j] = bf2f(scu[j]); }

            const float* sa = s_att + (size_t)i * 8 * BH + ro;
            const float* ta = t_att + (size_t)i * 8 * BH + ro;

            // batch-issue all independent global loads up front
            f32x4 sav[7], tav[8], tsp[4];
#pragma unroll
            for (int kk = 0; kk < 7; ++kk) sav[kk] = *(const f32x4*)(sa + (size_t)(kk + 1) * BH);
#pragma unroll
            for (int kk = 0; kk < 8; ++kk) tav[kk] = *(const f32x4*)(ta + (size_t)kk * BH);
#pragma unroll
            for (int jj = 0; jj < 4; ++jj)
                if (jj <= i) tsp[jj] = *(const f32x4*)(t_att + ((size_t)jj * 8 + 7) * BH + ro);

            // temporal logits: keys = s_att[i,1:] ++ [S]
            float lt[8];
#pragma unroll
            for (int kk = 0; kk < 7; ++kk)
                lt[kk] = wred(sav[kk][0] * sn[0] + sav[kk][1] * sn[1] + sav[kk][2] * sn[2] + sav[kk][3] * sn[3]) * scale;
            lt[7] = wred(Sc[0] * sn[0] + Sc[1] * sn[1] + Sc[2] * sn[2] + Sc[3] * sn[3]) * scale;

            float m = lt[0];
#pragma unroll
            for (int kk = 1; kk < 8; ++kk) m = fmaxf(m, lt[kk]);
            float w8[8], den = 0.f;
#pragma unroll
            for (int kk = 0; kk < 8; ++kk) { w8[kk] = __expf(lt[kk] - m); den += w8[kk]; }
            float inv = 1.f / den;

            // T_trend + T_fusion
            float Tt[4] = {0.f, 0.f, 0.f, 0.f};
#pragma unroll
            for (int kk = 0; kk < 8; ++kk)
#pragma unroll
                for (int j = 0; j < 4; ++j) Tt[j] += w8[kk] * tav[kk][j];
            us4 ot;
#pragma unroll
            for (int j = 0; j < 4; ++j) {
                float g = sigmoidf_(tn[j]);
                ot[j] = f2bf(tav[7][j] * g + (1.f - g) * Tt[j] * inv);
            }
            *(us4*)&tf_lds[rr][lane * 4] = ot;

            // spatial logits (precomputed, then plain softmax incl. 7-i zero entries)
            float lsp[4];
#pragma unroll
            for (int jj = 0; jj < 4; ++jj)
                if (jj <= i)
                    lsp[jj] = wred(tsp[jj][0] * tn[0] + tsp[jj][1] * tn[1] + tsp[jj][2] * tn[2] + tsp[jj][3] * tn[3]) * scale;
            float ms = 0.f;
#pragma unroll
            for (int jj = 0; jj < 4; ++jj)
                if (jj <= i) ms = fmaxf(ms, lsp[jj]);
            float dens = (float)(7 - i) * __expf(-ms);
            float St[4] = {0.f, 0.f, 0.f, 0.f};
#pragma unroll
            for (int jj = 0; jj < 4; ++jj)
                if (jj <= i) {
                    float w = __expf(lsp[jj] - ms);
                    dens += w;
                    us4 shu = *(const us4*)&S_lds[jj][rr][lane * 4];
#pragma unroll
                    for (int j = 0; j < 4; ++j) St[j] += w * bf2f(shu[j]);
                }
            float invs = 1.f / dens;
            us4 os;
#pragma unroll
            for (int j = 0; j < 4; ++j) {
                float g = sigmoidf_(sn[j]);
                os[j] = f2bf(Sc[j] * g + (1.f - g) * St[j] * invs);
            }
            *(us4*)&sf_lds[rr][lane * 4] = os;
        }
        __syncthreads();

        // ---- phase 3: triple GEMM + gated combine, 16 cols per wave ----
        {
            const u16* Wt3 = Wbf + (size_t)(9  + i) * 65536;
            const u16* Ws1 = Wbf + (size_t)(13 + i) * 65536;
            const u16* Ws3 = Wbf + (size_t)(17 + i) * 65536;
            f32x4 aT = {}, aG = {}, aS = {};
            for (int k0 = 0; k0 < 256; k0 += 32) {
                int k = k0 + kg * 8;
                short8 at = *(const short8*)(&tf_lds[lr][k]);
                short8 as = *(const short8*)(&sf_lds[lr][k]);
                size_t wo = (size_t)(n0 + lr) * 256 + k;
                aT = __builtin_amdgcn_mfma_f32_16x16x32_bf16(at, *(const short8*)(Wt3 + wo), aT, 0, 0, 0);
                aG = __builtin_amdgcn_mfma_f32_16x16x32_bf16(as, *(const short8*)(Ws1 + wo), aG, 0, 0, 0);
                aS = __builtin_amdgcn_mfma_f32_16x16x32_bf16(as, *(const short8*)(Ws3 + wo), aS, 0, 0, 0);
            }
            float bb1 = bt[i * 768 + 512 + n0 + lr];
            float bb2 = bs[i * 768 + n0 + lr];
            float bb3 = bs[i * 768 + 512 + n0 + lr];
#pragma unroll
            for (int r = 0; r < 4; ++r) {
                float gv = sigmoidf_(aG[r] + bb2);
                float v = gv * (aS[r] + bb3) + (1.f - gv) * (aT[r] + bb1);
                S_lds[i + 1][kg * 4 + r][n0 + lr] = f2bf(v);
            }
        }
        __syncthreads();
    }

    // ---- out = tanh(S4 @ out_w^T + out_b), f32 ----
    {
        const u16* Wo = Wbf + (size_t)21 * 65536;
        f32x4 acc = {};
        for (int k0 = 0; k0 < 256; k0 += 32) {
            int k = k0 + kg * 8;
            short8 a = *(const short8*)(&S_lds[4][lr][k]);
            short8 b = *(const short8*)(Wo + (size_t)(n0 + lr) * 256 + k);
            acc = __builtin_amdgcn_mfma_f32_16x16x32_bf16(a, b, acc, 0, 0, 0);
        }
        float bn = out_b[n0 + lr];
#pragma unroll
        for (int r = 0; r < 4; ++r)
            outp[(size_t)(row0 + kg * 4 + r) * 256 + n0 + lr] = tanhf(acc[r] + bn);
    }
}

extern "C" void kernel_launch(void* const* d_in, const int* in_sizes, int n_in,
                              void* d_out, int out_size, void* d_ws, size_t ws_size,
                              hipStream_t stream)
{
    (void)in_sizes; (void)n_in; (void)out_size; (void)ws_size;
    const float* x       = (const float*)d_in[0];
    const float* t_att   = (const float*)d_in[1];
    const float* s_att   = (const float*)d_in[2];
    const float* embed_w = (const float*)d_in[3];
    const float* embed_b = (const float*)d_in[4];
    const float* wtn     = (const float*)d_in[5];
    const float* btn     = (const float*)d_in[6];
    const float* wsn     = (const float*)d_in[7];
    const float* bsn     = (const float*)d_in[8];
    const float* wt      = (const float*)d_in[9];
    const float* bt      = (const float*)d_in[10];
    const float* ws_in   = (const float*)d_in[11];
    const float* bs      = (const float*)d_in[12];
    const float* out_w   = (const float*)d_in[13];
    const float* out_b   = (const float*)d_in[14];

    u16* Wbf = (u16*)d_ws;  // 22 * 65536 u16 = 2.88 MB

    convert_weights<<<1408, 256, 0, stream>>>(embed_w, wtn, wsn, wt, ws_in, out_w, Wbf);

    stau_mega<<<BATCH / 16, 1024, 0, stream>>>(
        x, t_att, s_att, Wbf, embed_b, btn, bsn, bt, bs, out_b, (float*)d_out);
}

// Round 5
// 305.699 us; speedup vs baseline: 1.3493x; 1.3493x over previous
//
#include <hip/hip_runtime.h>
#include <cmath>

typedef __attribute__((ext_vector_type(8))) short short8;
typedef __attribute__((ext_vector_type(4))) float f32x4;
typedef __attribute__((ext_vector_type(4))) unsigned short us4;
typedef unsigned short u16;

#define BATCH 8192
#define HDIM  256
static constexpr size_t BH = (size_t)BATCH * HDIM;  // 2,097,152

__device__ __forceinline__ u16 f2bf(float f) {
    union { float f; unsigned u; } v; v.f = f;
    unsigned r = v.u + 0x7FFFu + ((v.u >> 16) & 1u);
    return (u16)(r >> 16);
}
__device__ __forceinline__ float bf2f(u16 u) {
    union { unsigned u; float f; } v; v.u = ((unsigned)u) << 16;
    return v.f;
}
__device__ __forceinline__ float wred(float v) {
#pragma unroll
    for (int o = 32; o > 0; o >>= 1) v += __shfl_xor(v, o);
    return v;
}
__device__ __forceinline__ float sigmoidf_(float x) {
    return 1.f / (1.f + __expf(-x));
}
__device__ __forceinline__ short8 cvt8(const float* p) {
    f32x4 lo = *(const f32x4*)p, hi = *(const f32x4*)(p + 4);
    short8 t;
    t[0] = (short)f2bf(lo[0]); t[1] = (short)f2bf(lo[1]);
    t[2] = (short)f2bf(lo[2]); t[3] = (short)f2bf(lo[3]);
    t[4] = (short)f2bf(hi[0]); t[5] = (short)f2bf(hi[1]);
    t[6] = (short)f2bf(hi[2]); t[7] = (short)f2bf(hi[3]);
    return t;
}

// ---------------- weight conversion: pack all needed weights to bf16 ----------------
// dst layout (u16 units, 65536 per chunk):
//  c0: embed_w | c1..4: wtn[l] | c5..8: wsn[l] | c9..12: wt[l][512:768]
//  c13..16: ws[l][0:256] | c17..20: ws[l][512:768] | c21: out_w
__global__ __launch_bounds__(256) void convert_weights(
    const float* __restrict__ embed_w, const float* __restrict__ wtn,
    const float* __restrict__ wsn, const float* __restrict__ wt,
    const float* __restrict__ ws, const float* __restrict__ out_w,
    u16* __restrict__ dst)
{
    int idx = blockIdx.x * 256 + threadIdx.x;
    int e = idx * 4;
    if (e >= 22 * 65536) return;
    int c = e >> 16, o = e & 65535;
    const float* src;
    if (c == 0)      src = embed_w + o;
    else if (c < 5)  src = wtn + (size_t)(c - 1) * 65536 + o;
    else if (c < 9)  src = wsn + (size_t)(c - 5) * 65536 + o;
    else if (c < 13) src = wt + (size_t)(c - 9) * 768 * 256 + 512 * 256 + o;
    else if (c < 17) src = ws + (size_t)(c - 13) * 768 * 256 + o;
    else if (c < 21) src = ws + (size_t)(c - 17) * 768 * 256 + 512 * 256 + o;
    else             src = out_w + o;
    f32x4 v = *(const f32x4*)src;
    us4 r;
#pragma unroll
    for (int j = 0; j < 4; ++j) r[j] = f2bf(v[j]);
    *(us4*)(dst + e) = r;
}

// ---------------- mega kernel v3: 512 thr (8 waves), 16 rows, VGPR<=128 ----------------
#define PAD 264  // u16 row stride (528 B: 16B-aligned, breaks power-of-2 bank pattern)
__global__ __launch_bounds__(512, 4) void stau_mega(
    const float* __restrict__ x,
    const float* __restrict__ t_att, const float* __restrict__ s_att,
    const u16* __restrict__ Wbf,
    const float* __restrict__ embed_b,
    const float* __restrict__ btn, const float* __restrict__ bsn,
    const float* __restrict__ bt, const float* __restrict__ bs,
    const float* __restrict__ out_b,
    float* __restrict__ outp)
{
    __shared__ __align__(16) u16 S_lds[5][16][PAD];  // S history (bf16)
    __shared__ __align__(16) u16 sn_lds[16][PAD];    // s_next (bf16)
    __shared__ __align__(16) u16 tn_lds[16][PAD];    // t_next (bf16)
    __shared__ __align__(16) u16 tf_lds[16][PAD];    // T_fusion (bf16)
    __shared__ __align__(16) u16 sf_lds[16][PAD];    // S_fusion (bf16)

    const int lane = threadIdx.x & 63;
    const int wave = threadIdx.x >> 6;  // 0..7
    const int lr = lane & 15;
    const int kg = lane >> 4;
    const int row0 = blockIdx.x * 16;
    const float scale = 0.0625f;        // 1/sqrt(256)

    // ---- embed: S0 = x @ embed_w^T + embed_b (wave w -> cols 32w..32w+31) ----
    {
        const int n0 = wave * 32;
        f32x4 acc[2] = {};
        for (int k0 = 0; k0 < 256; k0 += 32) {
            int k = k0 + kg * 8;
            short8 a = cvt8(x + (size_t)(row0 + lr) * 256 + k);
#pragma unroll
            for (int nf = 0; nf < 2; ++nf) {
                short8 b = *(const short8*)(Wbf + (size_t)(n0 + nf * 16 + lr) * 256 + k);
                acc[nf] = __builtin_amdgcn_mfma_f32_16x16x32_bf16(a, b, acc[nf], 0, 0, 0);
            }
        }
#pragma unroll
        for (int nf = 0; nf < 2; ++nf) {
            int n = n0 + nf * 16 + lr;
            float bn = embed_b[n];
#pragma unroll
            for (int r = 0; r < 4; ++r)
                S_lds[0][kg * 4 + r][n] = f2bf(acc[nf][r] + bn);
        }
    }
    __syncthreads();

    for (int i = 0; i < 4; ++i) {
        // ---- phase 1: s_next (waves 0-3) / t_next (waves 4-7), 64 cols each ----
        {
            const int g = wave >> 2;          // 0: s_next, 1: t_next
            const int n0 = (wave & 3) * 64;
            const u16* Wm = Wbf + (size_t)((g ? 1 : 5) + i) * 65536;
            const float* bias = (g ? btn : bsn) + i * 256;
            f32x4 acc[4] = {};
            for (int k0 = 0; k0 < 256; k0 += 32) {
                int k = k0 + kg * 8;
                short8 a;
                if (g == 0) a = *(const short8*)(&S_lds[i][lr][k]);
                else        a = cvt8(t_att + ((size_t)i * 8 + 7) * BH + (size_t)(row0 + lr) * 256 + k);
#pragma unroll
                for (int nf = 0; nf < 4; ++nf) {
                    short8 b = *(const short8*)(Wm + (size_t)(n0 + nf * 16 + lr) * 256 + k);
                    acc[nf] = __builtin_amdgcn_mfma_f32_16x16x32_bf16(a, b, acc[nf], 0, 0, 0);
                }
            }
            u16 (*dst)[PAD] = g ? tn_lds : sn_lds;
#pragma unroll
            for (int nf = 0; nf < 4; ++nf) {
                int n = n0 + nf * 16 + lr;
                float bn = bias[n];
#pragma unroll
                for (int r = 0; r < 4; ++r)
                    dst[kg * 4 + r][n] = f2bf(acc[nf][r] + bn);
            }
        }
        __syncthreads();

        // ---- phase 2: attention + gating (wave w -> rows 2w, 2w+1) ----
        for (int rr = wave * 2; rr < wave * 2 + 2; ++rr) {
            const size_t ro = (size_t)(row0 + rr) * 256 + lane * 4;
            const float* sa = s_att + (size_t)i * 8 * BH + ro;
            const float* ta = t_att + (size_t)i * 8 * BH + ro;

            // batch-issue all independent global loads up front (fits 128-VGPR budget)
            f32x4 sav[7], tav[8], tspv[3];
#pragma unroll
            for (int kk = 0; kk < 7; ++kk) sav[kk] = *(const f32x4*)(sa + (size_t)(kk + 1) * BH);
#pragma unroll
            for (int kk = 0; kk < 8; ++kk) tav[kk] = *(const f32x4*)(ta + (size_t)kk * BH);
#pragma unroll
            for (int jj = 0; jj < 3; ++jj)
                if (jj < i) tspv[jj] = *(const f32x4*)(t_att + ((size_t)jj * 8 + 7) * BH + ro);

            us4 snu = *(const us4*)&sn_lds[rr][lane * 4];
            us4 tnu = *(const us4*)&tn_lds[rr][lane * 4];
            us4 scu = *(const us4*)&S_lds[i][rr][lane * 4];
            float sn[4], tn[4], Sc[4];
#pragma unroll
            for (int j = 0; j < 4; ++j) { sn[j] = bf2f(snu[j]); tn[j] = bf2f(tnu[j]); Sc[j] = bf2f(scu[j]); }

            // temporal logits: keys = s_att[i,1:] ++ [S]
            float lt[8];
#pragma unroll
            for (int kk = 0; kk < 7; ++kk)
                lt[kk] = wred(sav[kk][0] * sn[0] + sav[kk][1] * sn[1] + sav[kk][2] * sn[2] + sav[kk][3] * sn[3]) * scale;
            lt[7] = wred(Sc[0] * sn[0] + Sc[1] * sn[1] + Sc[2] * sn[2] + Sc[3] * sn[3]) * scale;

            float m = lt[0];
#pragma unroll
            for (int kk = 1; kk < 8; ++kk) m = fmaxf(m, lt[kk]);
            float w8[8], den = 0.f;
#pragma unroll
            for (int kk = 0; kk < 8; ++kk) { w8[kk] = __expf(lt[kk] - m); den += w8[kk]; }
            float inv = 1.f / den;

            // T_trend + T_fusion
            float Tt[4] = {0.f, 0.f, 0.f, 0.f};
#pragma unroll
            for (int kk = 0; kk < 8; ++kk)
#pragma unroll
                for (int j = 0; j < 4; ++j) Tt[j] += w8[kk] * tav[kk][j];
            us4 ot;
#pragma unroll
            for (int j = 0; j < 4; ++j) {
                float g = sigmoidf_(tn[j]);
                ot[j] = f2bf(tav[7][j] * g + (1.f - g) * Tt[j] * inv);
            }
            *(us4*)&tf_lds[rr][lane * 4] = ot;

            // spatial: keys = [zeros x (7-i), t_att[0,7]..t_att[i,7]]; t_att[i,7]==tav[7]
            float lsp[4];
#pragma unroll
            for (int jj = 0; jj < 3; ++jj)
                if (jj < i)
                    lsp[jj] = wred(tspv[jj][0] * tn[0] + tspv[jj][1] * tn[1] + tspv[jj][2] * tn[2] + tspv[jj][3] * tn[3]) * scale;
            lsp[3] = wred(tav[7][0] * tn[0] + tav[7][1] * tn[1] + tav[7][2] * tn[2] + tav[7][3] * tn[3]) * scale;

            float ms = fmaxf(0.f, lsp[3]);
#pragma unroll
            for (int jj = 0; jj < 3; ++jj)
                if (jj < i) ms = fmaxf(ms, lsp[jj]);
            float dens = (float)(7 - i) * __expf(-ms);
            float St[4] = {0.f, 0.f, 0.f, 0.f};
#pragma unroll
            for (int jj = 0; jj < 3; ++jj)
                if (jj < i) {
                    float w = __expf(lsp[jj] - ms);
                    dens += w;
                    us4 shu = *(const us4*)&S_lds[jj][rr][lane * 4];
#pragma unroll
                    for (int j = 0; j < 4; ++j) St[j] += w * bf2f(shu[j]);
                }
            {   // jj == i entry (uses current S_lds[i] and logit lsp[3])
                float w = __expf(lsp[3] - ms);
                dens += w;
#pragma unroll
                for (int j = 0; j < 4; ++j) St[j] += w * Sc[j];
            }
            float invs = 1.f / dens;
            us4 os;
#pragma unroll
            for (int j = 0; j < 4; ++j) {
                float g = sigmoidf_(sn[j]);
                os[j] = f2bf(Sc[j] * g + (1.f - g) * St[j] * invs);
            }
            *(us4*)&sf_lds[rr][lane * 4] = os;
        }
        __syncthreads();

        // ---- phase 3: triple GEMM + gated combine (wave w -> cols 32w..32w+31) ----
        {
            const int n0 = wave * 32;
            const u16* Wt3 = Wbf + (size_t)(9  + i) * 65536;
            const u16* Ws1 = Wbf + (size_t)(13 + i) * 65536;
            const u16* Ws3 = Wbf + (size_t)(17 + i) * 65536;
            f32x4 aT[2] = {}, aG[2] = {}, aS[2] = {};
            for (int k0 = 0; k0 < 256; k0 += 32) {
                int k = k0 + kg * 8;
                short8 at = *(const short8*)(&tf_lds[lr][k]);
                short8 as = *(const short8*)(&sf_lds[lr][k]);
#pragma unroll
                for (int nf = 0; nf < 2; ++nf) {
                    size_t wo = (size_t)(n0 + nf * 16 + lr) * 256 + k;
                    aT[nf] = __builtin_amdgcn_mfma_f32_16x16x32_bf16(at, *(const short8*)(Wt3 + wo), aT[nf], 0, 0, 0);
                    aG[nf] = __builtin_amdgcn_mfma_f32_16x16x32_bf16(as, *(const short8*)(Ws1 + wo), aG[nf], 0, 0, 0);
                    aS[nf] = __builtin_amdgcn_mfma_f32_16x16x32_bf16(as, *(const short8*)(Ws3 + wo), aS[nf], 0, 0, 0);
                }
            }
            const float* b1 = bt + i * 768 + 512;
            const float* b2 = bs + i * 768;
            const float* b3 = bs + i * 768 + 512;
#pragma unroll
            for (int nf = 0; nf < 2; ++nf) {
                int n = n0 + nf * 16 + lr;
                float bb1 = b1[n], bb2 = b2[n], bb3 = b3[n];
#pragma unroll
                for (int r = 0; r < 4; ++r) {
                    float gv = sigmoidf_(aG[nf][r] + bb2);
                    float v = gv * (aS[nf][r] + bb3) + (1.f - gv) * (aT[nf][r] + bb1);
                    S_lds[i + 1][kg * 4 + r][n] = f2bf(v);
                }
            }
        }
        __syncthreads();
    }

    // ---- out = tanh(S4 @ out_w^T + out_b), f32 ----
    {
        const int n0 = wave * 32;
        const u16* Wo = Wbf + (size_t)21 * 65536;
        f32x4 acc[2] = {};
        for (int k0 = 0; k0 < 256; k0 += 32) {
            int k = k0 + kg * 8;
            short8 a = *(const short8*)(&S_lds[4][lr][k]);
#pragma unroll
            for (int nf = 0; nf < 2; ++nf) {
                short8 b = *(const short8*)(Wo + (size_t)(n0 + nf * 16 + lr) * 256 + k);
                acc[nf] = __builtin_amdgcn_mfma_f32_16x16x32_bf16(a, b, acc[nf], 0, 0, 0);
            }
        }
#pragma unroll
        for (int nf = 0; nf < 2; ++nf) {
            int n = n0 + nf * 16 + lr;
            float bn = out_b[n];
#pragma unroll
            for (int r = 0; r < 4; ++r)
                outp[(size_t)(row0 + kg * 4 + r) * 256 + n] = tanhf(acc[nf][r] + bn);
        }
    }
}

extern "C" void kernel_launch(void* const* d_in, const int* in_sizes, int n_in,
                              void* d_out, int out_size, void* d_ws, size_t ws_size,
                              hipStream_t stream)
{
    (void)in_sizes; (void)n_in; (void)out_size; (void)ws_size;
    const float* x       = (const float*)d_in[0];
    const float* t_att   = (const float*)d_in[1];
    const float* s_att   = (const float*)d_in[2];
    const float* embed_w = (const float*)d_in[3];
    const float* embed_b = (const float*)d_in[4];
    const float* wtn     = (const float*)d_in[5];
    const float* btn     = (const float*)d_in[6];
    const float* wsn     = (const float*)d_in[7];
    const float* bsn     = (const float*)d_in[8];
    const float* wt      = (const float*)d_in[9];
    const float* bt      = (const float*)d_in[10];
    const float* ws_in   = (const float*)d_in[11];
    const float* bs      = (const float*)d_in[12];
    const float* out_w   = (const float*)d_in[13];
    const float* out_b   = (const float*)d_in[14];

    u16* Wbf = (u16*)d_ws;  // 22 * 65536 u16 = 2.88 MB

    convert_weights<<<1408, 256, 0, stream>>>(embed_w, wtn, wsn, wt, ws_in, out_w, Wbf);

    stau_mega<<<BATCH / 16, 512, 0, stream>>>(
        x, t_att, s_att, Wbf, embed_b, btn, bsn, bt, bs, out_b, (float*)d_out);
}